// Round 2
// baseline (308.082 us; speedup 1.0000x reference)
//
#include <hip/hip_runtime.h>
#include <stdint.h>

typedef __attribute__((ext_vector_type(4))) float f32x4;
typedef __attribute__((ext_vector_type(8))) __bf16 bf16x8;
typedef __attribute__((ext_vector_type(4))) unsigned short u16x4;
typedef __attribute__((ext_vector_type(8))) unsigned short u16x8;

#define DEV __device__ __forceinline__

DEV unsigned short f2bf(float f) {
  union { float f; unsigned int u; } v; v.f = f;
  unsigned int r = v.u + 0x7fffu + ((v.u >> 16) & 1u);
  return (unsigned short)(r >> 16);
}

DEV void gl_lds16(const void* g, void* l) {
  __builtin_amdgcn_global_load_lds(
      (const __attribute__((address_space(1))) unsigned int*)g,
      (__attribute__((address_space(3))) unsigned int*)l, 16, 0, 0);
}

#define SBAR() __builtin_amdgcn_s_barrier()
#define LGKM0() do { asm volatile("s_waitcnt lgkmcnt(0)" ::: "memory"); __builtin_amdgcn_sched_barrier(0); } while (0)
#define VMC6() do { asm volatile("s_waitcnt vmcnt(6)" ::: "memory"); __builtin_amdgcn_sched_barrier(0); } while (0)
#define VMC0() do { asm volatile("s_waitcnt vmcnt(0)" ::: "memory"); __builtin_amdgcn_sched_barrier(0); } while (0)

// ---------------- prep kernels ----------------

__global__ void prep_tabs(const float* __restrict__ gm,
                          float* __restrict__ costab, float* __restrict__ sintab,
                          float* __restrict__ wtab) {
  int idx = blockIdx.x * 256 + threadIdx.x;     // 4096*64 total
  int n = idx >> 6, c = idx & 63, j = c >> 1;
  float inv = powf(10000.0f, -(float)(2 * j) / 64.0f);
  float ang = (float)n * inv;
  costab[idx] = cosf(ang);
  sintab[idx] = sinf(ang);
  if (idx < 1024) {                              // wtab: [2][512]
    int b = idx >> 9, d = idx & 511;
    wtab[idx] = gm[b * 4096 + d] * powf(0.96f, (float)d);
  }
}

__global__ void cvt_x(const float* __restrict__ x, unsigned short* __restrict__ xb) {
  size_t i8 = ((size_t)blockIdx.x * 256 + threadIdx.x) * 8;
  float4 a = *(const float4*)(x + i8);
  float4 b = *(const float4*)(x + i8 + 4);
  u16x8 o;
  o[0] = f2bf(a.x); o[1] = f2bf(a.y); o[2] = f2bf(a.z); o[3] = f2bf(a.w);
  o[4] = f2bf(b.x); o[5] = f2bf(b.y); o[6] = f2bf(b.z); o[7] = f2bf(b.w);
  *(u16x8*)(xb + i8) = o;
}

// 4x 1024x1024 fp32 -> transposed bf16, blockIdx.z selects matrix
__global__ void transpose_cvt4(const float* __restrict__ s0, const float* __restrict__ s1,
                               const float* __restrict__ s2, const float* __restrict__ s3,
                               unsigned short* __restrict__ d0, unsigned short* __restrict__ d3) {
  __shared__ float tile[32][33];
  int z = blockIdx.z;
  const float* src = (z == 0) ? s0 : (z == 1) ? s1 : (z == 2) ? s2 : s3;
  unsigned short* dst = (z == 3) ? d3 : d0 + (size_t)z * 1024 * 1024;
  int tx = threadIdx.x & 31, ty = threadIdx.x >> 5;   // 32x8
  int c0 = blockIdx.x * 32, r0 = blockIdx.y * 32;
  #pragma unroll
  for (int j = 0; j < 4; j++)
    tile[ty + 8 * j][tx] = src[(size_t)(r0 + ty + 8 * j) * 1024 + c0 + tx];
  __syncthreads();
  #pragma unroll
  for (int j = 0; j < 4; j++)
    dst[(size_t)(c0 + ty + 8 * j) * 1024 + r0 + tx] = f2bf(tile[tx][ty + 8 * j]);
}

// ---------------- 256x256 8-phase GEMM (qkv + fused rope/relu/V^T epilogue) ----------------
// A: [8192][1024] bf16 row-major.  Bt: [3072][1024] bf16 row-major (=W^T).
// 512 threads = 8 waves (2 wm x 4 wn). BK=64, K=1024, 16 tiles, dbuf LDS 128 KiB.
// Half-tile regions 128x64 bf16 = 16 KiB: [dbuf][A/B][half]. XOR chunk swizzle ch^=(row&7).

DEV void stage_half(const unsigned short* __restrict__ g0, int kcol, char* regn, int tid) {
  #pragma unroll
  for (int i = 0; i < 2; i++) {
    int tg = i * 512 + tid;
    int row = tg >> 3;
    int ch = tg & 7;
    gl_lds16(g0 + (size_t)row * 1024 + kcol + ((ch ^ (row & 7)) << 3), regn + tg * 16);
  }
}

DEV void read_a4(bf16x8 (&af)[4][2], const char* regn, int wm, int lane) {
  #pragma unroll
  for (int f = 0; f < 4; f++) {
    int row = wm * 64 + f * 16 + (lane & 15);
    #pragma unroll
    for (int ks = 0; ks < 2; ks++) {
      int c = ks * 4 + (lane >> 4);
      af[f][ks] = *(const bf16x8*)(regn + row * 128 + ((c ^ (row & 7)) << 4));
    }
  }
}

DEV void read_b2(bf16x8 (&bfr)[2][2], const char* regn, int wn, int lane) {
  #pragma unroll
  for (int g = 0; g < 2; g++) {
    int row = wn * 32 + g * 16 + (lane & 15);
    #pragma unroll
    for (int ks = 0; ks < 2; ks++) {
      int c = ks * 4 + (lane >> 4);
      bfr[g][ks] = *(const bf16x8*)(regn + row * 128 + ((c ^ (row & 7)) << 4));
    }
  }
}

template<int MB, int NB>
DEV void mfma16(f32x4 (&acc)[8][4], const bf16x8 (&af)[4][2], const bf16x8 (&bfr)[2][2]) {
  #pragma unroll
  for (int ks = 0; ks < 2; ks++)
    #pragma unroll
    for (int f = 0; f < 4; f++)
      #pragma unroll
      for (int g = 0; g < 2; g++)
        acc[MB + f][NB + g] =
            __builtin_amdgcn_mfma_f32_16x16x32_bf16(af[f][ks], bfr[g][ks], acc[MB + f][NB + g], 0, 0, 0);
}

__global__ void __launch_bounds__(512, 2)
gemm256_qkv(const unsigned short* __restrict__ A,
            const unsigned short* __restrict__ Bt,
            unsigned short* __restrict__ q_out,
            unsigned short* __restrict__ k_out,
            unsigned short* __restrict__ vt_out,
            const float* __restrict__ costab,
            const float* __restrict__ sintab)
{
  extern __shared__ char smem[];
  constexpr int K = 1024, NT = 16;
  const int tid = threadIdx.x;
  const int lane = tid & 63;
  const int w = tid >> 6;
  const int wm = w >> 2, wn = w & 3;
  const int bm = blockIdx.x, bn = blockIdx.y;

  // LDS region: [dbuf][mat(A=0,B=1)][half]
  char* rg[2][2][2];
  #pragma unroll
  for (int d = 0; d < 2; d++)
    #pragma unroll
    for (int m = 0; m < 2; m++)
      #pragma unroll
      for (int h = 0; h < 2; h++)
        rg[d][m][h] = smem + d * 65536 + m * 32768 + h * 16384;

  const unsigned short* Ab = A + (size_t)bm * 256 * K;
  const unsigned short* Bb = Bt + (size_t)bn * 256 * K;
  const unsigned short* A0g = Ab;                 // A half0 rows
  const unsigned short* A1g = Ab + (size_t)128 * K;
  const unsigned short* B0g = Bb;
  const unsigned short* B1g = Bb + (size_t)128 * K;

  const f32x4 fz = {0.f, 0.f, 0.f, 0.f};
  f32x4 acc[8][4];
  #pragma unroll
  for (int i = 0; i < 8; i++)
    #pragma unroll
    for (int j = 0; j < 4; j++) acc[i][j] = fz;

  // ---- prologue: t0.{A0,B0,B1,A1}, t1.{A0,B1,A1}  (7 half-tiles = 14 loads/wave)
  stage_half(A0g, 0, rg[0][0][0], tid);
  stage_half(B0g, 0, rg[0][1][0], tid);
  stage_half(B1g, 0, rg[0][1][1], tid);
  stage_half(A1g, 0, rg[0][0][1], tid);
  stage_half(A0g, 64, rg[1][0][0], tid);
  stage_half(B1g, 64, rg[1][1][1], tid);
  stage_half(A1g, 64, rg[1][0][1], tid);
  VMC6();          // tile 0 fully landed (newest 3 = t1.{A0,B1,A1} may be in flight)
  SBAR();

  for (int t = 0; t < NT; ++t) {
    const int db = t & 1;
    bf16x8 af[4][2], bfr[2][2];

    // ---- P1 (rh0,ch0): read A0(8)+B0(4); stage (t+1).B0
    read_a4(af, rg[db][0][0], wm, lane);
    read_b2(bfr, rg[db][1][0], wn, lane);
    if (t + 1 < NT) stage_half(B0g, (t + 1) * 64, rg[db ^ 1][1][0], tid);
    SBAR(); LGKM0();
    __builtin_amdgcn_s_setprio(1);
    mfma16<0, 0>(acc, af, bfr);
    __builtin_amdgcn_s_setprio(0);
    SBAR();

    // ---- P2 (rh0,ch1): read B1(4); A reused; stage (t+2).A0
    read_b2(bfr, rg[db][1][1], wn, lane);
    if (t + 2 < NT) stage_half(A0g, (t + 2) * 64, rg[db][0][0], tid);
    SBAR(); LGKM0();
    __builtin_amdgcn_s_setprio(1);
    mfma16<0, 2>(acc, af, bfr);
    __builtin_amdgcn_s_setprio(0);
    SBAR();

    // ---- P3 (rh1,ch1): read A1(8); B1 reused; stage (t+2).B1
    read_a4(af, rg[db][0][1], wm, lane);
    if (t + 2 < NT) stage_half(B1g, (t + 2) * 64, rg[db][1][1], tid);
    SBAR(); LGKM0();
    __builtin_amdgcn_s_setprio(1);
    mfma16<4, 2>(acc, af, bfr);
    __builtin_amdgcn_s_setprio(0);
    SBAR();

    // ---- P4 (rh1,ch0): re-read B0(4); A1 reused; stage (t+2).A1; boundary vmcnt
    read_b2(bfr, rg[db][1][0], wn, lane);
    if (t + 2 < NT) stage_half(A1g, (t + 2) * 64, rg[db][0][1], tid);
    SBAR(); LGKM0();
    __builtin_amdgcn_s_setprio(1);
    mfma16<4, 0>(acc, af, bfr);
    __builtin_amdgcn_s_setprio(0);
    if (t < NT - 2) { VMC6(); } else { VMC0(); }
    SBAR();
  }

  // ---- epilogue: rope+relu -> Q/K, relu -> V^T
  #pragma unroll
  for (int n = 0; n < 4; n++) {
    int col = bn * 256 + (n >> 1) * 128 + wn * 32 + (n & 1) * 16 + (lane & 15);
    int which = col >> 10;                    // 0=Q 1=K 2=V (uniform per block: bn*256 tiles)
    int c = col & 1023;
    #pragma unroll
    for (int m = 0; m < 8; m++) {
      int row0 = bm * 256 + (m >> 2) * 128 + wm * 64 + (m & 3) * 16 + ((lane >> 4) << 2);
      float vals[4];
      #pragma unroll
      for (int r = 0; r < 4; r++) vals[r] = acc[m][n][r];
      if (which < 2) {
        if (c < 64) {                         // wave-uniform per fragment
          #pragma unroll
          for (int r = 0; r < 4; r++) {
            float p = __shfl_xor(vals[r], 1); // paired rope element (col^1)
            int nn = (row0 + r) & 4095;
            float cs = costab[nn * 64 + c];
            float sn = sintab[nn * 64 + c];
            float rh = (c & 1) ? p : -p;
            vals[r] = vals[r] * cs + rh * sn;
          }
        }
        unsigned short* dst = (which == 0) ? q_out : k_out;
        #pragma unroll
        for (int r = 0; r < 4; r++) {
          float v = vals[r] > 0.f ? vals[r] : 0.f;
          dst[(size_t)(row0 + r) * 1024 + c] = f2bf(v);
        }
      } else {
        u16x4 sv;
        #pragma unroll
        for (int r = 0; r < 4; r++) {
          float v = vals[r] > 0.f ? vals[r] : 0.f;
          sv[r] = f2bf(v);
        }
        *(u16x4*)(vt_out + (size_t)c * 8192 + row0) = sv;   // V^T (4 contiguous tokens)
      }
    }
  }
}

// ---------------- 128x128 GEMM (fc layer) ----------------
__global__ void __launch_bounds__(256, 2)
gemm128_fc(const unsigned short* __restrict__ A,
           const unsigned short* __restrict__ Bt,
           float* __restrict__ f_out,
           const float* __restrict__ bias)
{
  constexpr int K = 1024;
  __shared__ char smem[32768];
  char* a_sm = smem;
  char* b_sm = smem + 16384;
  const int tid = threadIdx.x;
  const int lane = tid & 63;
  const int w = tid >> 6;
  const int wm = w >> 1, wn = w & 1;
  const int bm = blockIdx.x, bn = blockIdx.y;

  const f32x4 fz = {0.f, 0.f, 0.f, 0.f};
  f32x4 acc[4][4];
  #pragma unroll
  for (int i = 0; i < 4; i++)
    #pragma unroll
    for (int j = 0; j < 4; j++) acc[i][j] = fz;

  const unsigned short* Abase = A + (size_t)bm * 128 * K;
  const unsigned short* Bbase = Bt + (size_t)bn * 128 * K;

  for (int k0 = 0; k0 < K; k0 += 64) {
    __syncthreads();
    #pragma unroll
    for (int i = 0; i < 4; i++) {
      int tg = i * 256 + tid;
      int row = tg >> 3;
      int sl = (tg & 7) ^ (row & 7);
      gl_lds16(Abase + (size_t)row * K + k0 + sl * 8, a_sm + tg * 16);
    }
    #pragma unroll
    for (int i = 0; i < 4; i++) {
      int tg = i * 256 + tid;
      int row = tg >> 3;
      int sl = (tg & 7) ^ (row & 7);
      gl_lds16(Bbase + (size_t)row * K + k0 + sl * 8, b_sm + tg * 16);
    }
    __syncthreads();
    #pragma unroll
    for (int ks = 0; ks < 2; ks++) {
      int kb = ks * 64 + ((lane >> 4) << 4);
      bf16x8 af[4], bfv[4];
      #pragma unroll
      for (int f = 0; f < 4; f++) {
        int ar = wm * 64 + f * 16 + (lane & 15);
        af[f] = *(const bf16x8*)(a_sm + ar * 128 + (kb ^ ((ar & 7) << 4)));
        int br = wn * 64 + f * 16 + (lane & 15);
        bfv[f] = *(const bf16x8*)(b_sm + br * 128 + (kb ^ ((br & 7) << 4)));
      }
      #pragma unroll
      for (int fm = 0; fm < 4; fm++)
        #pragma unroll
        for (int fn = 0; fn < 4; fn++)
          acc[fm][fn] = __builtin_amdgcn_mfma_f32_16x16x32_bf16(af[fm], bfv[fn], acc[fm][fn], 0, 0, 0);
    }
  }

  const int rbase = bm * 128 + wm * 64 + ((lane >> 4) << 2);
  const int cbase = bn * 128 + wn * 64;
  #pragma unroll
  for (int fn = 0; fn < 4; fn++) {
    int col = cbase + fn * 16 + (lane & 15);
    float bv = bias[col];
    #pragma unroll
    for (int fm = 0; fm < 4; fm++) {
      int row0 = rbase + fm * 16;
      #pragma unroll
      for (int r = 0; r < 4; r++)
        f_out[(size_t)(row0 + r) * 1024 + col] = acc[fm][fn][r] + bv;
    }
  }
}

// ---------------- windowed decay attention ----------------
// per block: 64 queries (q0..q0+63), keys kv0=q0-256 .. q0+63 (320 rows), 8 waves.
__global__ void __launch_bounds__(512, 2)
attn_kernel(const unsigned short* __restrict__ Qb,
            const unsigned short* __restrict__ Kb,
            const unsigned short* __restrict__ Vt,
            const float* __restrict__ wtab,
            const float* __restrict__ att_mask,
            unsigned short* __restrict__ Yb)
{
  __shared__ char smem[49152];
  __shared__ float wl[320];
  char* k_sm = smem;            // [320][64] bf16, XOR-swizzled (40960 B)
  char* q_sm = smem + 40960;    // [64][64]  bf16, XOR-swizzled (8192 B)
  char* p_sm = smem;            // [64][320] bf16, XOR-swizzled (aliases k_sm)

  const int tid = threadIdx.x;
  const int lane = tid & 63;
  const int w = tid >> 6;
  const int q0 = blockIdx.x * 64;
  const int b = blockIdx.y;
  const int base = b * 4096;
  const int kv0 = q0 - 256;

  if (tid < 320) wl[tid] = wtab[b * 512 + tid];

  const int wq = w >> 2, wk = w & 3;            // 2x4 wave grid for phase 1
  const f32x4 fz = {0.f, 0.f, 0.f, 0.f};
  f32x4 sacc[2][5];
  #pragma unroll
  for (int i = 0; i < 2; i++)
    #pragma unroll
    for (int j = 0; j < 5; j++) sacc[i][j] = fz;

  // phase 1: S = Q K^T over c-chunks of 64
  for (int c0 = 0; c0 < 1024; c0 += 64) {
    __syncthreads();
    {
      int row = tid >> 3;
      int sl = (tid & 7) ^ (row & 7);
      gl_lds16(Qb + (size_t)(base + q0 + row) * 1024 + c0 + sl * 8, q_sm + tid * 16);
    }
    #pragma unroll
    for (int i = 0; i < 5; i++) {
      int tg = i * 512 + tid;
      int row = tg >> 3;
      int sl = (tg & 7) ^ (row & 7);
      int m = kv0 + row; m = m < 0 ? 0 : m;     // clamped rows get weight 0 later
      gl_lds16(Kb + (size_t)(base + m) * 1024 + c0 + sl * 8, k_sm + tg * 16);
    }
    __syncthreads();
    #pragma unroll
    for (int ks = 0; ks < 2; ks++) {
      int kb = ks * 64 + ((lane >> 4) << 4);
      bf16x8 af[2], bfv[5];
      #pragma unroll
      for (int f = 0; f < 2; f++) {
        int ar = wq * 32 + f * 16 + (lane & 15);
        af[f] = *(const bf16x8*)(q_sm + ar * 128 + (kb ^ ((ar & 7) << 4)));
      }
      #pragma unroll
      for (int f = 0; f < 5; f++) {
        int br = wk * 80 + f * 16 + (lane & 15);
        bfv[f] = *(const bf16x8*)(k_sm + br * 128 + (kb ^ ((br & 7) << 4)));
      }
      #pragma unroll
      for (int fm = 0; fm < 2; fm++)
        #pragma unroll
        for (int fj = 0; fj < 5; fj++)
          sacc[fm][fj] = __builtin_amdgcn_mfma_f32_16x16x32_bf16(af[fm], bfv[fj], sacc[fm][fj], 0, 0, 0);
    }
  }
  __syncthreads();

  // weight + bf16 -> P in LDS
  #pragma unroll
  for (int fm = 0; fm < 2; fm++) {
    #pragma unroll
    for (int fj = 0; fj < 5; fj++) {
      int jj = wk * 80 + fj * 16 + (lane & 15);
      int m = kv0 + jj;
      #pragma unroll
      for (int r = 0; r < 4; r++) {
        int i = wq * 32 + fm * 16 + ((lane >> 4) << 2) + r;
        int d = 256 + i - jj;                    // n - m
        float wgt = (d >= 0 && m >= 0) ? wl[d] : 0.f;
        *(unsigned short*)(p_sm + i * 640 + ((jj * 2) ^ ((i & 7) << 4))) =
            f2bf(sacc[fm][fj][r] * wgt);
      }
    }
  }
  __syncthreads();

  // phase 2: y = P @ V (V^T fragments from global)
  f32x4 yacc[4][8];
  #pragma unroll
  for (int i = 0; i < 4; i++)
    #pragma unroll
    for (int j = 0; j < 8; j++) yacc[i][j] = fz;

  for (int kt = 0; kt < 10; kt++) {
    int kb = kt * 64 + ((lane >> 4) << 4);
    bf16x8 pa[4], vb[8];
    #pragma unroll
    for (int f = 0; f < 4; f++) {
      int i = f * 16 + (lane & 15);
      pa[f] = *(const bf16x8*)(p_sm + i * 640 + (kb ^ ((i & 7) << 4)));
    }
    int kvi = kt * 32 + ((lane >> 4) << 3);
    int m = kv0 + kvi; m = m < 0 ? 0 : m;        // whole 8-group clamps together
    #pragma unroll
    for (int f = 0; f < 8; f++) {
      int col = w * 128 + f * 16 + (lane & 15);
      vb[f] = *(const bf16x8*)(Vt + (size_t)col * 8192 + base + m);
    }
    #pragma unroll
    for (int fm = 0; fm < 4; fm++)
      #pragma unroll
      for (int fn = 0; fn < 8; fn++)
        yacc[fm][fn] = __builtin_amdgcn_mfma_f32_16x16x32_bf16(pa[fm], vb[fn], yacc[fm][fn], 0, 0, 0);
  }

  #pragma unroll
  for (int fm = 0; fm < 4; fm++) {
    #pragma unroll
    for (int r = 0; r < 4; r++) {
      int n = q0 + fm * 16 + ((lane >> 4) << 2) + r;
      float am = att_mask[base + n];
      #pragma unroll
      for (int fn = 0; fn < 8; fn++) {
        int col = w * 128 + fn * 16 + (lane & 15);
        Yb[(size_t)(base + n) * 1024 + col] = f2bf(yacc[fm][fn][r] * am);
      }
    }
  }
}

// ---------------- launcher ----------------
extern "C" void kernel_launch(void* const* d_in, const int* in_sizes, int n_in,
                              void* d_out, int out_size, void* d_ws, size_t ws_size,
                              hipStream_t stream)
{
  (void)in_sizes; (void)n_in; (void)out_size;
  const float* x   = (const float*)d_in[0];
  const float* gm  = (const float*)d_in[1];
  const float* am  = (const float*)d_in[2];
  const float* wq  = (const float*)d_in[3];
  const float* wk  = (const float*)d_in[4];
  const float* wv  = (const float*)d_in[5];
  const float* fcw = (const float*)d_in[6];
  const float* fcb = (const float*)d_in[7];
  float* out = (float*)d_out;

  char* p = (char*)d_ws;
  unsigned short* xb    = (unsigned short*)p; p += (size_t)8192 * 1024 * 2;
  unsigned short* Qb    = (unsigned short*)p; p += (size_t)8192 * 1024 * 2;
  unsigned short* Kb    = (unsigned short*)p; p += (size_t)8192 * 1024 * 2;
  unsigned short* Vt    = (unsigned short*)p; p += (size_t)8192 * 1024 * 2;
  unsigned short* Ybuf  = (unsigned short*)p; p += (size_t)8192 * 1024 * 2;
  unsigned short* WqkvT = (unsigned short*)p; p += (size_t)3072 * 1024 * 2;
  unsigned short* FcwT  = (unsigned short*)p; p += (size_t)1024 * 1024 * 2;
  float* costab = (float*)p; p += (size_t)4096 * 64 * 4;
  float* sintab = (float*)p; p += (size_t)4096 * 64 * 4;
  float* wtab   = (float*)p; p += 4096;
  if ((size_t)(p - (char*)d_ws) > ws_size) return;   // ws too small: fail cleanly

  hipFuncSetAttribute((const void*)gemm256_qkv,
                      hipFuncAttributeMaxDynamicSharedMemorySize, 131072);

  prep_tabs<<<1024, 256, 0, stream>>>(gm, costab, sintab, wtab);
  cvt_x<<<4096, 256, 0, stream>>>(x, xb);
  transpose_cvt4<<<dim3(32, 32, 4), 256, 0, stream>>>(wq, wk, wv, fcw, WqkvT, FcwT);

  gemm256_qkv<<<dim3(32, 12), 512, 131072, stream>>>(xb, WqkvT, Qb, Kb, Vt, costab, sintab);
  attn_kernel<<<dim3(64, 2), 512, 0, stream>>>(Qb, Kb, Vt, wtab, am, Ybuf);
  gemm128_fc<<<dim3(64, 8), 256, 0, stream>>>(Ybuf, FcwT, out, fcb);
}

// Round 4
// 276.347 us; speedup vs baseline: 1.1148x; 1.1148x over previous
//
#include <hip/hip_runtime.h>
#include <stdint.h>

typedef __attribute__((ext_vector_type(4))) float f32x4;
typedef __attribute__((ext_vector_type(8))) __bf16 bf16x8;
typedef __attribute__((ext_vector_type(4))) unsigned short u16x4;
typedef __attribute__((ext_vector_type(8))) unsigned short u16x8;

#define DEV __device__ __forceinline__

DEV unsigned short f2bf(float f) {
  union { float f; unsigned int u; } v; v.f = f;
  unsigned int r = v.u + 0x7fffu + ((v.u >> 16) & 1u);
  return (unsigned short)(r >> 16);
}

DEV void gl_lds16(const void* g, void* l) {
  __builtin_amdgcn_global_load_lds(
      (const __attribute__((address_space(1))) unsigned int*)g,
      (__attribute__((address_space(3))) unsigned int*)l, 16, 0, 0);
}

// ---------------- prep kernels ----------------

__global__ void prep_tabs(const float* __restrict__ gm,
                          float* __restrict__ costab, float* __restrict__ sintab,
                          float* __restrict__ wtab) {
  int idx = blockIdx.x * 256 + threadIdx.x;     // 4096*64 total
  int n = idx >> 6, c = idx & 63, j = c >> 1;
  float inv = powf(10000.0f, -(float)(2 * j) / 64.0f);
  float ang = (float)n * inv;
  costab[idx] = cosf(ang);
  sintab[idx] = sinf(ang);
  if (idx < 1024) {                              // wtab: [2][512]
    int b = idx >> 9, d = idx & 511;
    wtab[idx] = gm[b * 4096 + d] * powf(0.96f, (float)d);
  }
}

__global__ void cvt_x(const float* __restrict__ x, unsigned short* __restrict__ xb) {
  size_t i8 = ((size_t)blockIdx.x * 256 + threadIdx.x) * 8;
  float4 a = *(const float4*)(x + i8);
  float4 b = *(const float4*)(x + i8 + 4);
  u16x8 o;
  o[0] = f2bf(a.x); o[1] = f2bf(a.y); o[2] = f2bf(a.z); o[3] = f2bf(a.w);
  o[4] = f2bf(b.x); o[5] = f2bf(b.y); o[6] = f2bf(b.z); o[7] = f2bf(b.w);
  *(u16x8*)(xb + i8) = o;
}

// 4x 1024x1024 fp32 -> transposed bf16, blockIdx.z selects matrix
__global__ void transpose_cvt4(const float* __restrict__ s0, const float* __restrict__ s1,
                               const float* __restrict__ s2, const float* __restrict__ s3,
                               unsigned short* __restrict__ d0, unsigned short* __restrict__ d3) {
  __shared__ float tile[32][33];
  int z = blockIdx.z;
  const float* src = (z == 0) ? s0 : (z == 1) ? s1 : (z == 2) ? s2 : s3;
  unsigned short* dst = (z == 3) ? d3 : d0 + (size_t)z * 1024 * 1024;
  int tx = threadIdx.x & 31, ty = threadIdx.x >> 5;   // 32x8
  int c0 = blockIdx.x * 32, r0 = blockIdx.y * 32;
  #pragma unroll
  for (int j = 0; j < 4; j++)
    tile[ty + 8 * j][tx] = src[(size_t)(r0 + ty + 8 * j) * 1024 + c0 + tx];
  __syncthreads();
  #pragma unroll
  for (int j = 0; j < 4; j++)
    dst[(size_t)(c0 + ty + 8 * j) * 1024 + r0 + tx] = f2bf(tile[tx][ty + 8 * j]);
}

// ---------------- 128x128 GEMM (proven m97 structure), XCD-swizzled 1-D grid ----------------
// EPI 0: qkv epilogue (rope+relu -> Qb,Kb row-major; relu -> Vt transposed). grid 1536.
// EPI 1: fc epilogue (+bias, fp32 out). grid 512.
template<int EPI>
__global__ void __launch_bounds__(256, 2)
gemm128(const unsigned short* __restrict__ A,
        const unsigned short* __restrict__ Bt,
        unsigned short* __restrict__ q_out,
        unsigned short* __restrict__ k_out,
        unsigned short* __restrict__ vt_out,
        const float* __restrict__ costab,
        const float* __restrict__ sintab,
        float* __restrict__ f_out,
        const float* __restrict__ bias)
{
  constexpr int K = 1024;
  __shared__ char smem[32768];
  char* a_sm = smem;
  char* b_sm = smem + 16384;
  const int tid = threadIdx.x;
  const int lane = tid & 63;
  const int w = tid >> 6;
  const int wm = w >> 1, wn = w & 1;

  // XCD-bijective swizzle: contiguous chunk of blocks per XCD (grid % 8 == 0)
  const int id = blockIdx.x;
  const int chunk = gridDim.x >> 3;
  const int nid = (id & 7) * chunk + (id >> 3);
  const int bm = nid & 63;
  const int bn = nid >> 6;

  const f32x4 fz = {0.f, 0.f, 0.f, 0.f};
  f32x4 acc[4][4];
  #pragma unroll
  for (int i = 0; i < 4; i++)
    #pragma unroll
    for (int j = 0; j < 4; j++) acc[i][j] = fz;

  const unsigned short* Abase = A + (size_t)bm * 128 * K;
  const unsigned short* Bbase = Bt + (size_t)bn * 128 * K;

  for (int k0 = 0; k0 < K; k0 += 64) {
    __syncthreads();
    #pragma unroll
    for (int i = 0; i < 4; i++) {
      int tg = i * 256 + tid;
      int row = tg >> 3;
      int sl = (tg & 7) ^ (row & 7);            // pre-swizzled global source (m173 pattern)
      gl_lds16(Abase + (size_t)row * K + k0 + sl * 8, a_sm + tg * 16);
    }
    #pragma unroll
    for (int i = 0; i < 4; i++) {
      int tg = i * 256 + tid;
      int row = tg >> 3;
      int sl = (tg & 7) ^ (row & 7);
      gl_lds16(Bbase + (size_t)row * K + k0 + sl * 8, b_sm + tg * 16);
    }
    __syncthreads();
    #pragma unroll
    for (int ks = 0; ks < 2; ks++) {
      int kb = ks * 64 + ((lane >> 4) << 4);
      bf16x8 af[4], bfv[4];
      #pragma unroll
      for (int f = 0; f < 4; f++) {
        int ar = wm * 64 + f * 16 + (lane & 15);
        af[f] = *(const bf16x8*)(a_sm + ar * 128 + (kb ^ ((ar & 7) << 4)));
        int br = wn * 64 + f * 16 + (lane & 15);
        bfv[f] = *(const bf16x8*)(b_sm + br * 128 + (kb ^ ((br & 7) << 4)));
      }
      #pragma unroll
      for (int fm = 0; fm < 4; fm++)
        #pragma unroll
        for (int fn = 0; fn < 4; fn++)
          acc[fm][fn] = __builtin_amdgcn_mfma_f32_16x16x32_bf16(af[fm], bfv[fn], acc[fm][fn], 0, 0, 0);
    }
  }

  const int rbase = bm * 128 + wm * 64 + ((lane >> 4) << 2);
  const int cbase = bn * 128 + wn * 64;

  if constexpr (EPI == 0) {
    #pragma unroll
    for (int fn = 0; fn < 4; fn++) {
      int col = cbase + fn * 16 + (lane & 15);
      int which = col >> 10;                     // 0=Q 1=K 2=V
      int c = col & 1023;
      #pragma unroll
      for (int fm = 0; fm < 4; fm++) {
        int row0 = rbase + fm * 16;
        float vals[4];
        #pragma unroll
        for (int r = 0; r < 4; r++) vals[r] = acc[fm][fn][r];
        if (which < 2) {
          if (c < 64) {                          // wave-uniform per fragment
            #pragma unroll
            for (int r = 0; r < 4; r++) {
              float p = __shfl_xor(vals[r], 1);  // paired rope element (col^1)
              int n = (row0 + r) & 4095;
              float cs = costab[n * 64 + c];
              float sn = sintab[n * 64 + c];
              float rh = (c & 1) ? p : -p;
              vals[r] = vals[r] * cs + rh * sn;
            }
          }
          unsigned short* dst = (which == 0) ? q_out : k_out;
          #pragma unroll
          for (int r = 0; r < 4; r++) {
            float v = vals[r] > 0.f ? vals[r] : 0.f;
            dst[(size_t)(row0 + r) * 1024 + c] = f2bf(v);
          }
        } else {
          u16x4 sv;
          #pragma unroll
          for (int r = 0; r < 4; r++) {
            float v = vals[r] > 0.f ? vals[r] : 0.f;
            sv[r] = f2bf(v);
          }
          *(u16x4*)(vt_out + (size_t)c * 8192 + row0) = sv;   // V^T (4 contiguous tokens)
        }
      }
    }
  } else {
    #pragma unroll
    for (int fn = 0; fn < 4; fn++) {
      int col = cbase + fn * 16 + (lane & 15);
      float bv = bias[col];
      #pragma unroll
      for (int fm = 0; fm < 4; fm++) {
        int row0 = rbase + fm * 16;
        #pragma unroll
        for (int r = 0; r < 4; r++)
          f_out[(size_t)(row0 + r) * 1024 + col] = acc[fm][fn][r] + bv;
      }
    }
  }
}

// ---------------- barrier-free windowed decay attention ----------------
// QBLK=32 queries/block, window = 320 keys (256 back + 64 pad), grid 256 = 1 block/CU.
// Q/K/V fragments read directly from global (L1/L2-resident); P in swizzled LDS.
// 8 waves: (wq = w>>2) in {0,1} -> 16 q-rows; (wk = w&3) -> 80 keys (5 frags).
__global__ void __launch_bounds__(512, 2)
attn_kernel(const unsigned short* __restrict__ Qb,
            const unsigned short* __restrict__ Kb,
            const unsigned short* __restrict__ Vt,
            const float* __restrict__ wtab,
            const float* __restrict__ att_mask,
            unsigned short* __restrict__ Yb)
{
  __shared__ alignas(16) unsigned char p_sm[32 * 640];   // P [32][320] bf16, XOR-swizzled
  __shared__ float wl[512];

  const int tid = threadIdx.x;
  const int lane = tid & 63;
  const int w = tid >> 6;

  // XCD-bijective swizzle: 32 consecutive q-blocks per XCD
  const int id = blockIdx.x + blockIdx.y * 128;          // 256 blocks
  const int nid = (id & 7) * 32 + (id >> 3);
  const int qb = nid & 127;
  const int b = nid >> 7;

  const int q0 = qb * 32;
  const int base = b * 4096;
  const int kv0 = q0 - 256;

  if (tid < 512) wl[tid] = wtab[b * 512 + tid];

  const int wq = w >> 2, wk = w & 3;
  const int l15 = lane & 15, lhi = lane >> 4;

  // ---- phase 1: S = Q K^T, fragments straight from global, no barriers ----
  const unsigned short* qptr =
      Qb + (size_t)(base + q0 + wq * 16 + l15) * 1024 + lhi * 8;
  const unsigned short* krow[5];
  #pragma unroll
  for (int f = 0; f < 5; f++) {
    int m = kv0 + wk * 80 + f * 16 + l15;
    m = m < 0 ? 0 : (m > 4095 ? 4095 : m);               // clamped rows weighted 0 later
    krow[f] = Kb + (size_t)(base + m) * 1024 + lhi * 8;
  }

  const f32x4 fz = {0.f, 0.f, 0.f, 0.f};
  f32x4 sacc[5];
  #pragma unroll
  for (int f = 0; f < 5; f++) sacc[f] = fz;

  for (int kk = 0; kk < 32; ++kk) {
    bf16x8 af = *(const bf16x8*)(qptr + kk * 32);
    #pragma unroll
    for (int f = 0; f < 5; f++) {
      bf16x8 bfv = *(const bf16x8*)(krow[f] + kk * 32);
      sacc[f] = __builtin_amdgcn_mfma_f32_16x16x32_bf16(af, bfv, sacc[f], 0, 0, 0);
    }
  }

  __syncthreads();   // wl ready; p_sm free

  // ---- weight + bf16 -> P in LDS ----
  #pragma unroll
  for (int f = 0; f < 5; f++) {
    int jj = wk * 80 + f * 16 + l15;                     // key index in window
    int m = kv0 + jj;
    #pragma unroll
    for (int r = 0; r < 4; r++) {
      int i = wq * 16 + lhi * 4 + r;                     // q row in block
      int d = 256 + i - jj;                              // n - m
      float wgt = (d >= 0 && m >= 0) ? wl[d] : 0.f;
      *(unsigned short*)(p_sm + i * 640 + ((jj * 2) ^ ((i & 7) << 4))) =
          f2bf(sacc[f][r] * wgt);
    }
  }
  __syncthreads();

  // ---- phase 2: y = P @ V, V^T fragments from global ----
  f32x4 yacc[2][8];
  #pragma unroll
  for (int i = 0; i < 2; i++)
    #pragma unroll
    for (int j = 0; j < 8; j++) yacc[i][j] = fz;

  const bool fastv = (kv0 >= 0) && (kv0 <= 3776);
  const unsigned short* vptr[8];
  #pragma unroll
  for (int f = 0; f < 8; f++) {
    int col = w * 128 + f * 16 + l15;
    vptr[f] = Vt + (size_t)col * 8192 + base + kv0 + lhi * 8;
  }

  for (int kt = 0; kt < 10; ++kt) {
    bf16x8 pa[2], vb[8];
    #pragma unroll
    for (int fm = 0; fm < 2; fm++) {
      int row = fm * 16 + l15;
      int cp = kt * 64 + lhi * 16;
      pa[fm] = *(const bf16x8*)(p_sm + row * 640 + (cp ^ ((row & 7) << 4)));
    }
    if (fastv) {
      #pragma unroll
      for (int f = 0; f < 8; f++) vb[f] = *(const bf16x8*)(vptr[f] + kt * 32);
    } else {
      int m = kv0 + kt * 32 + lhi * 8;
      m = m < 0 ? 0 : (m > 4088 ? 4088 : m);             // 8-token group clamp
      #pragma unroll
      for (int f = 0; f < 8; f++) {
        int col = w * 128 + f * 16 + l15;
        vb[f] = *(const bf16x8*)(Vt + (size_t)col * 8192 + base + m);
      }
    }
    #pragma unroll
    for (int fm = 0; fm < 2; fm++)
      #pragma unroll
      for (int fn = 0; fn < 8; fn++)
        yacc[fm][fn] = __builtin_amdgcn_mfma_f32_16x16x32_bf16(pa[fm], vb[fn], yacc[fm][fn], 0, 0, 0);
  }

  // ---- epilogue ----
  #pragma unroll
  for (int fm = 0; fm < 2; fm++) {
    #pragma unroll
    for (int r = 0; r < 4; r++) {
      int n = q0 + fm * 16 + lhi * 4 + r;
      float am = att_mask[base + n];
      #pragma unroll
      for (int fn = 0; fn < 8; fn++) {
        int col = w * 128 + fn * 16 + l15;
        Yb[(size_t)(base + n) * 1024 + col] = f2bf(yacc[fm][fn][r] * am);
      }
    }
  }
}

// ---------------- launcher ----------------
extern "C" void kernel_launch(void* const* d_in, const int* in_sizes, int n_in,
                              void* d_out, int out_size, void* d_ws, size_t ws_size,
                              hipStream_t stream)
{
  (void)in_sizes; (void)n_in; (void)out_size;
  const float* x   = (const float*)d_in[0];
  const float* gm  = (const float*)d_in[1];
  const float* am  = (const float*)d_in[2];
  const float* wq  = (const float*)d_in[3];
  const float* wk  = (const float*)d_in[4];
  const float* wv  = (const float*)d_in[5];
  const float* fcw = (const float*)d_in[6];
  const float* fcb = (const float*)d_in[7];
  float* out = (float*)d_out;

  char* p = (char*)d_ws;
  unsigned short* xb    = (unsigned short*)p; p += (size_t)8192 * 1024 * 2;
  unsigned short* Qb    = (unsigned short*)p; p += (size_t)8192 * 1024 * 2;
  unsigned short* Kb    = (unsigned short*)p; p += (size_t)8192 * 1024 * 2;
  unsigned short* Vt    = (unsigned short*)p; p += (size_t)8192 * 1024 * 2;
  unsigned short* Ybuf  = (unsigned short*)p; p += (size_t)8192 * 1024 * 2;
  unsigned short* WqkvT = (unsigned short*)p; p += (size_t)3072 * 1024 * 2;
  unsigned short* FcwT  = (unsigned short*)p; p += (size_t)1024 * 1024 * 2;
  float* costab = (float*)p; p += (size_t)4096 * 64 * 4;
  float* sintab = (float*)p; p += (size_t)4096 * 64 * 4;
  float* wtab   = (float*)p; p += 4096;
  if ((size_t)(p - (char*)d_ws) > ws_size) return;   // ws too small: fail cleanly

  prep_tabs<<<1024, 256, 0, stream>>>(gm, costab, sintab, wtab);
  cvt_x<<<4096, 256, 0, stream>>>(x, xb);
  transpose_cvt4<<<dim3(32, 32, 4), 256, 0, stream>>>(wq, wk, wv, fcw, WqkvT, FcwT);

  gemm128<0><<<1536, 256, 0, stream>>>(xb, WqkvT, Qb, Kb, Vt, costab, sintab, nullptr, nullptr);
  attn_kernel<<<dim3(128, 2), 512, 0, stream>>>(Qb, Kb, Vt, wtab, am, Ybuf);
  gemm128<1><<<512, 256, 0, stream>>>(Ybuf, FcwT, nullptr, nullptr, nullptr, nullptr, nullptr, out, fcb);
}

// Round 5
// 259.139 us; speedup vs baseline: 1.1889x; 1.0664x over previous
//
#include <hip/hip_runtime.h>
#include <stdint.h>

typedef __attribute__((ext_vector_type(4))) float f32x4;
typedef __attribute__((ext_vector_type(8))) __bf16 bf16x8;
typedef __attribute__((ext_vector_type(4))) unsigned short u16x4;
typedef __attribute__((ext_vector_type(8))) unsigned short u16x8;

#define DEV __device__ __forceinline__

DEV unsigned short f2bf(float f) {
  union { float f; unsigned int u; } v; v.f = f;
  unsigned int r = v.u + 0x7fffu + ((v.u >> 16) & 1u);
  return (unsigned short)(r >> 16);
}

DEV void gl_lds16(const void* g, void* l) {
  __builtin_amdgcn_global_load_lds(
      (const __attribute__((address_space(1))) unsigned int*)g,
      (__attribute__((address_space(3))) unsigned int*)l, 16, 0, 0);
}

// ---------------- prep kernels ----------------

__global__ void prep_tabs(const float* __restrict__ gm,
                          float* __restrict__ costab, float* __restrict__ sintab,
                          float* __restrict__ wtab) {
  int idx = blockIdx.x * 256 + threadIdx.x;     // 4096*64 total
  int n = idx >> 6, c = idx & 63, j = c >> 1;
  float inv = powf(10000.0f, -(float)(2 * j) / 64.0f);
  float ang = (float)n * inv;
  costab[idx] = cosf(ang);
  sintab[idx] = sinf(ang);
  if (idx < 1024) {                              // wtab: [2][512]
    int b = idx >> 9, d = idx & 511;
    wtab[idx] = gm[b * 4096 + d] * powf(0.96f, (float)d);
  }
}

__global__ void cvt_x(const float* __restrict__ x, unsigned short* __restrict__ xb) {
  size_t i8 = ((size_t)blockIdx.x * 256 + threadIdx.x) * 8;
  float4 a = *(const float4*)(x + i8);
  float4 b = *(const float4*)(x + i8 + 4);
  u16x8 o;
  o[0] = f2bf(a.x); o[1] = f2bf(a.y); o[2] = f2bf(a.z); o[3] = f2bf(a.w);
  o[4] = f2bf(b.x); o[5] = f2bf(b.y); o[6] = f2bf(b.z); o[7] = f2bf(b.w);
  *(u16x8*)(xb + i8) = o;
}

// 4x 1024x1024 fp32 -> transposed bf16, blockIdx.z selects matrix
__global__ void transpose_cvt4(const float* __restrict__ s0, const float* __restrict__ s1,
                               const float* __restrict__ s2, const float* __restrict__ s3,
                               unsigned short* __restrict__ d0, unsigned short* __restrict__ d3) {
  __shared__ float tile[32][33];
  int z = blockIdx.z;
  const float* src = (z == 0) ? s0 : (z == 1) ? s1 : (z == 2) ? s2 : s3;
  unsigned short* dst = (z == 3) ? d3 : d0 + (size_t)z * 1024 * 1024;
  int tx = threadIdx.x & 31, ty = threadIdx.x >> 5;   // 32x8
  int c0 = blockIdx.x * 32, r0 = blockIdx.y * 32;
  #pragma unroll
  for (int j = 0; j < 4; j++)
    tile[ty + 8 * j][tx] = src[(size_t)(r0 + ty + 8 * j) * 1024 + c0 + tx];
  __syncthreads();
  #pragma unroll
  for (int j = 0; j < 4; j++)
    dst[(size_t)(c0 + ty + 8 * j) * 1024 + r0 + tx] = f2bf(tile[tx][ty + 8 * j]);
}

// ---------------- 128x128 GEMM (proven m97 structure, round-1 2-D grid) ----------------
// 4 blocks/CU via __launch_bounds__(256,4): VGPR 60 <= 128-budget, 4x32KB LDS <= 160KB.
// EPI 0: qkv epilogue (rope+relu -> Qb,Kb row-major; relu -> Vt transposed). grid (64,24).
// EPI 1: fc epilogue (+bias, fp32 out). grid (64,8).
template<int EPI>
__global__ void __launch_bounds__(256, 4)
gemm128(const unsigned short* __restrict__ A,
        const unsigned short* __restrict__ Bt,
        unsigned short* __restrict__ q_out,
        unsigned short* __restrict__ k_out,
        unsigned short* __restrict__ vt_out,
        const float* __restrict__ costab,
        const float* __restrict__ sintab,
        float* __restrict__ f_out,
        const float* __restrict__ bias)
{
  constexpr int K = 1024;
  __shared__ char smem[32768];
  char* a_sm = smem;
  char* b_sm = smem + 16384;
  const int tid = threadIdx.x;
  const int lane = tid & 63;
  const int w = tid >> 6;
  const int wm = w >> 1, wn = w & 1;
  const int bm = blockIdx.x, bn = blockIdx.y;

  const f32x4 fz = {0.f, 0.f, 0.f, 0.f};
  f32x4 acc[4][4];
  #pragma unroll
  for (int i = 0; i < 4; i++)
    #pragma unroll
    for (int j = 0; j < 4; j++) acc[i][j] = fz;

  const unsigned short* Abase = A + (size_t)bm * 128 * K;
  const unsigned short* Bbase = Bt + (size_t)bn * 128 * K;

  for (int k0 = 0; k0 < K; k0 += 64) {
    __syncthreads();
    #pragma unroll
    for (int i = 0; i < 4; i++) {
      int tg = i * 256 + tid;
      int row = tg >> 3;
      int sl = (tg & 7) ^ (row & 7);            // pre-swizzled global source (m173 pattern)
      gl_lds16(Abase + (size_t)row * K + k0 + sl * 8, a_sm + tg * 16);
    }
    #pragma unroll
    for (int i = 0; i < 4; i++) {
      int tg = i * 256 + tid;
      int row = tg >> 3;
      int sl = (tg & 7) ^ (row & 7);
      gl_lds16(Bbase + (size_t)row * K + k0 + sl * 8, b_sm + tg * 16);
    }
    __syncthreads();
    #pragma unroll
    for (int ks = 0; ks < 2; ks++) {
      int kb = ks * 64 + ((lane >> 4) << 4);
      bf16x8 af[4], bfv[4];
      #pragma unroll
      for (int f = 0; f < 4; f++) {
        int ar = wm * 64 + f * 16 + (lane & 15);
        af[f] = *(const bf16x8*)(a_sm + ar * 128 + (kb ^ ((ar & 7) << 4)));
        int br = wn * 64 + f * 16 + (lane & 15);
        bfv[f] = *(const bf16x8*)(b_sm + br * 128 + (kb ^ ((br & 7) << 4)));
      }
      #pragma unroll
      for (int fm = 0; fm < 4; fm++)
        #pragma unroll
        for (int fn = 0; fn < 4; fn++)
          acc[fm][fn] = __builtin_amdgcn_mfma_f32_16x16x32_bf16(af[fm], bfv[fn], acc[fm][fn], 0, 0, 0);
    }
  }

  const int rbase = bm * 128 + wm * 64 + ((lane >> 4) << 2);
  const int cbase = bn * 128 + wn * 64;

  if constexpr (EPI == 0) {
    #pragma unroll
    for (int fn = 0; fn < 4; fn++) {
      int col = cbase + fn * 16 + (lane & 15);
      int which = col >> 10;                     // 0=Q 1=K 2=V
      int c = col & 1023;
      #pragma unroll
      for (int fm = 0; fm < 4; fm++) {
        int row0 = rbase + fm * 16;
        float vals[4];
        #pragma unroll
        for (int r = 0; r < 4; r++) vals[r] = acc[fm][fn][r];
        if (which < 2) {
          if (c < 64) {                          // wave-uniform per fragment
            #pragma unroll
            for (int r = 0; r < 4; r++) {
              float p = __shfl_xor(vals[r], 1);  // paired rope element (col^1)
              int n = (row0 + r) & 4095;
              float cs = costab[n * 64 + c];
              float sn = sintab[n * 64 + c];
              float rh = (c & 1) ? p : -p;
              vals[r] = vals[r] * cs + rh * sn;
            }
          }
          unsigned short* dst = (which == 0) ? q_out : k_out;
          #pragma unroll
          for (int r = 0; r < 4; r++) {
            float v = vals[r] > 0.f ? vals[r] : 0.f;
            dst[(size_t)(row0 + r) * 1024 + c] = f2bf(v);
          }
        } else {
          u16x4 sv;
          #pragma unroll
          for (int r = 0; r < 4; r++) {
            float v = vals[r] > 0.f ? vals[r] : 0.f;
            sv[r] = f2bf(v);
          }
          *(u16x4*)(vt_out + (size_t)c * 8192 + row0) = sv;   // V^T (4 contiguous tokens)
        }
      }
    }
  } else {
    #pragma unroll
    for (int fn = 0; fn < 4; fn++) {
      int col = cbase + fn * 16 + (lane & 15);
      float bv = bias[col];
      #pragma unroll
      for (int fm = 0; fm < 4; fm++) {
        int row0 = rbase + fm * 16;
        #pragma unroll
        for (int r = 0; r < 4; r++)
          f_out[(size_t)(row0 + r) * 1024 + col] = acc[fm][fn][r] + bv;
      }
    }
  }
}

// ---------------- barrier-free windowed decay attention ----------------
// QBLK=32 queries/block, window = 320 keys (256 back + 64 pad), grid 256 = 1 block/CU.
// Q/K/V fragments read directly from global (L1/L2-resident); P in swizzled LDS.
// 8 waves: (wq = w>>2) in {0,1} -> 16 q-rows; (wk = w&3) -> 80 keys (5 frags).
__global__ void __launch_bounds__(512, 2)
attn_kernel(const unsigned short* __restrict__ Qb,
            const unsigned short* __restrict__ Kb,
            const unsigned short* __restrict__ Vt,
            const float* __restrict__ wtab,
            const float* __restrict__ att_mask,
            unsigned short* __restrict__ Yb)
{
  __shared__ alignas(16) unsigned char p_sm[32 * 640];   // P [32][320] bf16, XOR-swizzled
  __shared__ float wl[512];

  const int tid = threadIdx.x;
  const int lane = tid & 63;
  const int w = tid >> 6;

  // XCD-bijective swizzle: 32 consecutive q-blocks per XCD (neighbors share K window)
  const int id = blockIdx.x + blockIdx.y * 128;          // 256 blocks
  const int nid = (id & 7) * 32 + (id >> 3);
  const int qb = nid & 127;
  const int b = nid >> 7;

  const int q0 = qb * 32;
  const int base = b * 4096;
  const int kv0 = q0 - 256;

  if (tid < 512) wl[tid] = wtab[b * 512 + tid];

  const int wq = w >> 2, wk = w & 3;
  const int l15 = lane & 15, lhi = lane >> 4;

  // ---- phase 1: S = Q K^T, fragments straight from global, no barriers ----
  const unsigned short* qptr =
      Qb + (size_t)(base + q0 + wq * 16 + l15) * 1024 + lhi * 8;
  const unsigned short* krow[5];
  #pragma unroll
  for (int f = 0; f < 5; f++) {
    int m = kv0 + wk * 80 + f * 16 + l15;
    m = m < 0 ? 0 : (m > 4095 ? 4095 : m);               // clamped rows weighted 0 later
    krow[f] = Kb + (size_t)(base + m) * 1024 + lhi * 8;
  }

  const f32x4 fz = {0.f, 0.f, 0.f, 0.f};
  f32x4 sacc[5];
  #pragma unroll
  for (int f = 0; f < 5; f++) sacc[f] = fz;

  for (int kk = 0; kk < 32; ++kk) {
    bf16x8 af = *(const bf16x8*)(qptr + kk * 32);
    #pragma unroll
    for (int f = 0; f < 5; f++) {
      bf16x8 bfv = *(const bf16x8*)(krow[f] + kk * 32);
      sacc[f] = __builtin_amdgcn_mfma_f32_16x16x32_bf16(af, bfv, sacc[f], 0, 0, 0);
    }
  }

  __syncthreads();   // wl ready; p_sm free

  // ---- weight + bf16 -> P in LDS ----
  #pragma unroll
  for (int f = 0; f < 5; f++) {
    int jj = wk * 80 + f * 16 + l15;                     // key index in window
    int m = kv0 + jj;
    #pragma unroll
    for (int r = 0; r < 4; r++) {
      int i = wq * 16 + lhi * 4 + r;                     // q row in block
      int d = 256 + i - jj;                              // n - m
      float wgt = (d >= 0 && m >= 0) ? wl[d] : 0.f;
      *(unsigned short*)(p_sm + i * 640 + ((jj * 2) ^ ((i & 7) << 4))) =
          f2bf(sacc[f][r] * wgt);
    }
  }
  __syncthreads();

  // ---- phase 2: y = P @ V, V^T fragments from global ----
  f32x4 yacc[2][8];
  #pragma unroll
  for (int i = 0; i < 2; i++)
    #pragma unroll
    for (int j = 0; j < 8; j++) yacc[i][j] = fz;

  const bool fastv = (kv0 >= 0) && (kv0 <= 3776);
  const unsigned short* vptr[8];
  #pragma unroll
  for (int f = 0; f < 8; f++) {
    int col = w * 128 + f * 16 + l15;
    vptr[f] = Vt + (size_t)col * 8192 + base + kv0 + lhi * 8;
  }

  for (int kt = 0; kt < 10; ++kt) {
    bf16x8 pa[2], vb[8];
    #pragma unroll
    for (int fm = 0; fm < 2; fm++) {
      int row = fm * 16 + l15;
      int cp = kt * 64 + lhi * 16;
      pa[fm] = *(const bf16x8*)(p_sm + row * 640 + (cp ^ ((row & 7) << 4)));
    }
    if (fastv) {
      #pragma unroll
      for (int f = 0; f < 8; f++) vb[f] = *(const bf16x8*)(vptr[f] + kt * 32);
    } else {
      int m = kv0 + kt * 32 + lhi * 8;
      m = m < 0 ? 0 : (m > 4088 ? 4088 : m);             // 8-token group clamp
      #pragma unroll
      for (int f = 0; f < 8; f++) {
        int col = w * 128 + f * 16 + l15;
        vb[f] = *(const bf16x8*)(Vt + (size_t)col * 8192 + base + m);
      }
    }
    #pragma unroll
    for (int fm = 0; fm < 2; fm++)
      #pragma unroll
      for (int fn = 0; fn < 8; fn++)
        yacc[fm][fn] = __builtin_amdgcn_mfma_f32_16x16x32_bf16(pa[fm], vb[fn], yacc[fm][fn], 0, 0, 0);
  }

  // ---- epilogue ----
  #pragma unroll
  for (int fm = 0; fm < 2; fm++) {
    #pragma unroll
    for (int r = 0; r < 4; r++) {
      int n = q0 + fm * 16 + lhi * 4 + r;
      float am = att_mask[base + n];
      #pragma unroll
      for (int fn = 0; fn < 8; fn++) {
        int col = w * 128 + fn * 16 + l15;
        Yb[(size_t)(base + n) * 1024 + col] = f2bf(yacc[fm][fn][r] * am);
      }
    }
  }
}

// ---------------- launcher ----------------
extern "C" void kernel_launch(void* const* d_in, const int* in_sizes, int n_in,
                              void* d_out, int out_size, void* d_ws, size_t ws_size,
                              hipStream_t stream)
{
  (void)in_sizes; (void)n_in; (void)out_size;
  const float* x   = (const float*)d_in[0];
  const float* gm  = (const float*)d_in[1];
  const float* am  = (const float*)d_in[2];
  const float* wq  = (const float*)d_in[3];
  const float* wk  = (const float*)d_in[4];
  const float* wv  = (const float*)d_in[5];
  const float* fcw = (const float*)d_in[6];
  const float* fcb = (const float*)d_in[7];
  float* out = (float*)d_out;

  char* p = (char*)d_ws;
  unsigned short* xb    = (unsigned short*)p; p += (size_t)8192 * 1024 * 2;
  unsigned short* Qb    = (unsigned short*)p; p += (size_t)8192 * 1024 * 2;
  unsigned short* Kb    = (unsigned short*)p; p += (size_t)8192 * 1024 * 2;
  unsigned short* Vt    = (unsigned short*)p; p += (size_t)8192 * 1024 * 2;
  unsigned short* Ybuf  = (unsigned short*)p; p += (size_t)8192 * 1024 * 2;
  unsigned short* WqkvT = (unsigned short*)p; p += (size_t)3072 * 1024 * 2;
  unsigned short* FcwT  = (unsigned short*)p; p += (size_t)1024 * 1024 * 2;
  float* costab = (float*)p; p += (size_t)4096 * 64 * 4;
  float* sintab = (float*)p; p += (size_t)4096 * 64 * 4;
  float* wtab   = (float*)p; p += 4096;
  if ((size_t)(p - (char*)d_ws) > ws_size) return;   // ws too small: fail cleanly

  prep_tabs<<<1024, 256, 0, stream>>>(gm, costab, sintab, wtab);
  cvt_x<<<4096, 256, 0, stream>>>(x, xb);
  transpose_cvt4<<<dim3(32, 32, 4), 256, 0, stream>>>(wq, wk, wv, fcw, WqkvT, FcwT);

  gemm128<0><<<dim3(64, 24), 256, 0, stream>>>(xb, WqkvT, Qb, Kb, Vt, costab, sintab, nullptr, nullptr);
  attn_kernel<<<dim3(128, 2), 512, 0, stream>>>(Qb, Kb, Vt, wtab, am, Ybuf);
  gemm128<1><<<dim3(64, 8), 256, 0, stream>>>(Ybuf, FcwT, nullptr, nullptr, nullptr, nullptr, nullptr, out, fcb);
}

// Round 6
// 257.058 us; speedup vs baseline: 1.1985x; 1.0081x over previous
//
#include <hip/hip_runtime.h>
#include <stdint.h>

typedef __attribute__((ext_vector_type(4))) float f32x4;
typedef __attribute__((ext_vector_type(8))) __bf16 bf16x8;
typedef __attribute__((ext_vector_type(4))) unsigned short u16x4;
typedef __attribute__((ext_vector_type(8))) unsigned short u16x8;

#define DEV __device__ __forceinline__

DEV unsigned short f2bf(float f) {
  union { float f; unsigned int u; } v; v.f = f;
  unsigned int r = v.u + 0x7fffu + ((v.u >> 16) & 1u);
  return (unsigned short)(r >> 16);
}

DEV void gl_lds16(const void* g, void* l) {
  __builtin_amdgcn_global_load_lds(
      (const __attribute__((address_space(1))) unsigned int*)g,
      (__attribute__((address_space(3))) unsigned int*)l, 16, 0, 0);
}

#define SBAR() __builtin_amdgcn_s_barrier()
#define LGKM0() asm volatile("s_waitcnt lgkmcnt(0)" ::: "memory")
#define VMC6() asm volatile("s_waitcnt vmcnt(6)" ::: "memory")
#define VMC0() asm volatile("s_waitcnt vmcnt(0)" ::: "memory")

// ---------------- prep kernels ----------------

__global__ void prep_tabs(const float* __restrict__ gm,
                          float* __restrict__ costab, float* __restrict__ sintab,
                          float* __restrict__ wtab) {
  int idx = blockIdx.x * 256 + threadIdx.x;     // 4096*64 total
  int n = idx >> 6, c = idx & 63, j = c >> 1;
  float inv = powf(10000.0f, -(float)(2 * j) / 64.0f);
  float ang = (float)n * inv;
  costab[idx] = cosf(ang);
  sintab[idx] = sinf(ang);
  if (idx < 1024) {                              // wtab: [2][512]
    int b = idx >> 9, d = idx & 511;
    wtab[idx] = gm[b * 4096 + d] * powf(0.96f, (float)d);
  }
}

__global__ void cvt_x(const float* __restrict__ x, unsigned short* __restrict__ xb) {
  size_t i8 = ((size_t)blockIdx.x * 256 + threadIdx.x) * 8;
  float4 a = *(const float4*)(x + i8);
  float4 b = *(const float4*)(x + i8 + 4);
  u16x8 o;
  o[0] = f2bf(a.x); o[1] = f2bf(a.y); o[2] = f2bf(a.z); o[3] = f2bf(a.w);
  o[4] = f2bf(b.x); o[5] = f2bf(b.y); o[6] = f2bf(b.z); o[7] = f2bf(b.w);
  *(u16x8*)(xb + i8) = o;
}

// 4x 1024x1024 fp32 -> transposed bf16, blockIdx.z selects matrix
__global__ void transpose_cvt4(const float* __restrict__ s0, const float* __restrict__ s1,
                               const float* __restrict__ s2, const float* __restrict__ s3,
                               unsigned short* __restrict__ d0, unsigned short* __restrict__ d3) {
  __shared__ float tile[32][33];
  int z = blockIdx.z;
  const float* src = (z == 0) ? s0 : (z == 1) ? s1 : (z == 2) ? s2 : s3;
  unsigned short* dst = (z == 3) ? d3 : d0 + (size_t)z * 1024 * 1024;
  int tx = threadIdx.x & 31, ty = threadIdx.x >> 5;   // 32x8
  int c0 = blockIdx.x * 32, r0 = blockIdx.y * 32;
  #pragma unroll
  for (int j = 0; j < 4; j++)
    tile[ty + 8 * j][tx] = src[(size_t)(r0 + ty + 8 * j) * 1024 + c0 + tx];
  __syncthreads();
  #pragma unroll
  for (int j = 0; j < 4; j++)
    dst[(size_t)(c0 + ty + 8 * j) * 1024 + r0 + tx] = f2bf(tile[tx][ty + 8 * j]);
}

// ---------------- 256x256 8-phase GEMM (qkv + fused rope/relu/V^T epilogue) ----------------
// A: [8192][1024] bf16 row-major.  Bt: [3072][1024] bf16 row-major (=W^T).
// 512 threads = 8 waves (2 wm x 4 wn). BK=64, 16 K-tiles, dbuf LDS 128 KiB, 1 block/CU.
// Static region pointers (rule #20), plain waitcnt asm (no sched_barrier — m141).

DEV void stage_half(const unsigned short* __restrict__ g0, int kcol, char* regn, int tid) {
  #pragma unroll
  for (int i = 0; i < 2; i++) {
    int tg = i * 512 + tid;
    int row = tg >> 3;
    int ch = tg & 7;
    gl_lds16(g0 + (size_t)row * 1024 + kcol + ((ch ^ (row & 7)) << 3), regn + tg * 16);
  }
}

DEV void read_a4(bf16x8 (&af)[4][2], const char* regn, int wm, int lane) {
  #pragma unroll
  for (int f = 0; f < 4; f++) {
    int row = wm * 64 + f * 16 + (lane & 15);
    #pragma unroll
    for (int ks = 0; ks < 2; ks++) {
      int c = ks * 4 + (lane >> 4);
      af[f][ks] = *(const bf16x8*)(regn + row * 128 + ((c ^ (row & 7)) << 4));
    }
  }
}

DEV void read_b2(bf16x8 (&bfr)[2][2], const char* regn, int wn, int lane) {
  #pragma unroll
  for (int g = 0; g < 2; g++) {
    int row = wn * 32 + g * 16 + (lane & 15);
    #pragma unroll
    for (int ks = 0; ks < 2; ks++) {
      int c = ks * 4 + (lane >> 4);
      bfr[g][ks] = *(const bf16x8*)(regn + row * 128 + ((c ^ (row & 7)) << 4));
    }
  }
}

template<int MB, int NB>
DEV void mfma16(f32x4 (&acc)[8][4], const bf16x8 (&af)[4][2], const bf16x8 (&bfr)[2][2]) {
  #pragma unroll
  for (int ks = 0; ks < 2; ks++)
    #pragma unroll
    for (int f = 0; f < 4; f++)
      #pragma unroll
      for (int g = 0; g < 2; g++)
        acc[MB + f][NB + g] =
            __builtin_amdgcn_mfma_f32_16x16x32_bf16(af[f][ks], bfr[g][ks], acc[MB + f][NB + g], 0, 0, 0);
}

__global__ void __launch_bounds__(512, 2)
gemm256_qkv(const unsigned short* __restrict__ A,
            const unsigned short* __restrict__ Bt,
            unsigned short* __restrict__ q_out,
            unsigned short* __restrict__ k_out,
            unsigned short* __restrict__ vt_out,
            const float* __restrict__ costab,
            const float* __restrict__ sintab)
{
  extern __shared__ char smem[];
  constexpr int NT = 16;
  const int tid = threadIdx.x;
  const int lane = tid & 63;
  const int w = tid >> 6;
  const int wm = w >> 2, wn = w & 3;
  const int bm = blockIdx.x, bn = blockIdx.y;

  // static LDS region pointers (no runtime indexing)
  char* const a0_0 = smem;
  char* const a1_0 = smem + 16384;
  char* const b0_0 = smem + 32768;
  char* const b1_0 = smem + 49152;
  char* const a0_1 = smem + 65536;
  char* const a1_1 = smem + 81920;
  char* const b0_1 = smem + 98304;
  char* const b1_1 = smem + 114688;

  const unsigned short* Ab = A + (size_t)bm * 256 * 1024;
  const unsigned short* Bb = Bt + (size_t)bn * 256 * 1024;
  const unsigned short* A0g = Ab;
  const unsigned short* A1g = Ab + (size_t)128 * 1024;
  const unsigned short* B0g = Bb;
  const unsigned short* B1g = Bb + (size_t)128 * 1024;

  const f32x4 fz = {0.f, 0.f, 0.f, 0.f};
  f32x4 acc[8][4];
  #pragma unroll
  for (int i = 0; i < 8; i++)
    #pragma unroll
    for (int j = 0; j < 4; j++) acc[i][j] = fz;

  // ---- prologue: t0.{A0,B0,B1,A1}, t1.{A0,B1,A1} (t1.B0 staged in t0.P1)
  stage_half(A0g, 0, a0_0, tid);
  stage_half(B0g, 0, b0_0, tid);
  stage_half(B1g, 0, b1_0, tid);
  stage_half(A1g, 0, a1_0, tid);
  stage_half(A0g, 64, a0_1, tid);
  stage_half(B1g, 64, b1_1, tid);
  stage_half(A1g, 64, a1_1, tid);
  VMC6();          // tile 0 fully landed
  SBAR();

  // tile body: cur-buffer regions static; stages: P1->next.B0, P2-4->cur (t+2 same parity)
#define TILE_BODY(cA0, cA1, cB0, cB1, nB0, T)                                   \
  {                                                                             \
    bf16x8 af[4][2], bfr[2][2];                                                 \
    /* P1 (rh0,ch0) */                                                          \
    read_a4(af, cA0, wm, lane);                                                 \
    read_b2(bfr, cB0, wn, lane);                                                \
    if ((T) + 1 < NT) stage_half(B0g, ((T) + 1) * 64, nB0, tid);                \
    SBAR(); LGKM0();                                                            \
    __builtin_amdgcn_s_setprio(1);                                              \
    mfma16<0, 0>(acc, af, bfr);                                                 \
    __builtin_amdgcn_s_setprio(0);                                              \
    SBAR();                                                                     \
    /* P2 (rh0,ch1): A regs reused */                                           \
    read_b2(bfr, cB1, wn, lane);                                                \
    if ((T) + 2 < NT) stage_half(A0g, ((T) + 2) * 64, cA0, tid);                \
    SBAR(); LGKM0();                                                            \
    __builtin_amdgcn_s_setprio(1);                                              \
    mfma16<0, 2>(acc, af, bfr);                                                 \
    __builtin_amdgcn_s_setprio(0);                                              \
    SBAR();                                                                     \
    /* P3 (rh1,ch1): B regs reused */                                           \
    read_a4(af, cA1, wm, lane);                                                 \
    if ((T) + 2 < NT) stage_half(B1g, ((T) + 2) * 64, cB1, tid);                \
    SBAR(); LGKM0();                                                            \
    __builtin_amdgcn_s_setprio(1);                                              \
    mfma16<4, 2>(acc, af, bfr);                                                 \
    __builtin_amdgcn_s_setprio(0);                                              \
    SBAR();                                                                     \
    /* P4 (rh1,ch0): A regs reused; boundary vmcnt */                           \
    read_b2(bfr, cB0, wn, lane);                                                \
    if ((T) + 2 < NT) stage_half(A1g, ((T) + 2) * 64, cA1, tid);                \
    SBAR(); LGKM0();                                                            \
    __builtin_amdgcn_s_setprio(1);                                              \
    mfma16<4, 0>(acc, af, bfr);                                                 \
    __builtin_amdgcn_s_setprio(0);                                              \
    if ((T) < NT - 2) { VMC6(); } else { VMC0(); }                              \
    SBAR();                                                                     \
  }

  for (int tp = 0; tp < NT / 2; ++tp) {
    TILE_BODY(a0_0, a1_0, b0_0, b1_0, b0_1, 2 * tp);
    TILE_BODY(a0_1, a1_1, b0_1, b1_1, b0_0, 2 * tp + 1);
  }
#undef TILE_BODY

  // ---- epilogue: rope+relu -> Q/K, relu -> V^T
  #pragma unroll
  for (int n = 0; n < 4; n++) {
    int col = bn * 256 + (n >> 1) * 128 + wn * 32 + (n & 1) * 16 + (lane & 15);
    int which = col >> 10;                    // 0=Q 1=K 2=V (block-uniform)
    int c = col & 1023;
    #pragma unroll
    for (int m = 0; m < 8; m++) {
      int row0 = bm * 256 + (m >> 2) * 128 + wm * 64 + (m & 3) * 16 + ((lane >> 4) << 2);
      float vals[4];
      #pragma unroll
      for (int r = 0; r < 4; r++) vals[r] = acc[m][n][r];
      if (which < 2) {
        if (c < 64) {                         // wave-uniform per fragment
          #pragma unroll
          for (int r = 0; r < 4; r++) {
            float p = __shfl_xor(vals[r], 1); // paired rope element (col^1)
            int nn = (row0 + r) & 4095;
            float cs = costab[nn * 64 + c];
            float sn = sintab[nn * 64 + c];
            float rh = (c & 1) ? p : -p;
            vals[r] = vals[r] * cs + rh * sn;
          }
        }
        unsigned short* dst = (which == 0) ? q_out : k_out;
        #pragma unroll
        for (int r = 0; r < 4; r++) {
          float v = vals[r] > 0.f ? vals[r] : 0.f;
          dst[(size_t)(row0 + r) * 1024 + c] = f2bf(v);
        }
      } else {
        u16x4 sv;
        #pragma unroll
        for (int r = 0; r < 4; r++) {
          float v = vals[r] > 0.f ? vals[r] : 0.f;
          sv[r] = f2bf(v);
        }
        *(u16x4*)(vt_out + (size_t)c * 8192 + row0) = sv;   // V^T (4 contiguous tokens)
      }
    }
  }
}

// ---------------- 128x128 GEMM (proven m97 structure, r1 config) — fc layer ----------------
__global__ void __launch_bounds__(256, 2)
gemm128_fc(const unsigned short* __restrict__ A,
           const unsigned short* __restrict__ Bt,
           float* __restrict__ f_out,
           const float* __restrict__ bias)
{
  constexpr int K = 1024;
  __shared__ char smem[32768];
  char* a_sm = smem;
  char* b_sm = smem + 16384;
  const int tid = threadIdx.x;
  const int lane = tid & 63;
  const int w = tid >> 6;
  const int wm = w >> 1, wn = w & 1;
  const int bm = blockIdx.x, bn = blockIdx.y;

  const f32x4 fz = {0.f, 0.f, 0.f, 0.f};
  f32x4 acc[4][4];
  #pragma unroll
  for (int i = 0; i < 4; i++)
    #pragma unroll
    for (int j = 0; j < 4; j++) acc[i][j] = fz;

  const unsigned short* Abase = A + (size_t)bm * 128 * K;
  const unsigned short* Bbase = Bt + (size_t)bn * 128 * K;

  for (int k0 = 0; k0 < K; k0 += 64) {
    __syncthreads();
    #pragma unroll
    for (int i = 0; i < 4; i++) {
      int tg = i * 256 + tid;
      int row = tg >> 3;
      int sl = (tg & 7) ^ (row & 7);
      gl_lds16(Abase + (size_t)row * K + k0 + sl * 8, a_sm + tg * 16);
    }
    #pragma unroll
    for (int i = 0; i < 4; i++) {
      int tg = i * 256 + tid;
      int row = tg >> 3;
      int sl = (tg & 7) ^ (row & 7);
      gl_lds16(Bbase + (size_t)row * K + k0 + sl * 8, b_sm + tg * 16);
    }
    __syncthreads();
    #pragma unroll
    for (int ks = 0; ks < 2; ks++) {
      int kb = ks * 64 + ((lane >> 4) << 4);
      bf16x8 af[4], bfv[4];
      #pragma unroll
      for (int f = 0; f < 4; f++) {
        int ar = wm * 64 + f * 16 + (lane & 15);
        af[f] = *(const bf16x8*)(a_sm + ar * 128 + (kb ^ ((ar & 7) << 4)));
        int br = wn * 64 + f * 16 + (lane & 15);
        bfv[f] = *(const bf16x8*)(b_sm + br * 128 + (kb ^ ((br & 7) << 4)));
      }
      #pragma unroll
      for (int fm = 0; fm < 4; fm++)
        #pragma unroll
        for (int fn = 0; fn < 4; fn++)
          acc[fm][fn] = __builtin_amdgcn_mfma_f32_16x16x32_bf16(af[fm], bfv[fn], acc[fm][fn], 0, 0, 0);
    }
  }

  const int rbase = bm * 128 + wm * 64 + ((lane >> 4) << 2);
  const int cbase = bn * 128 + wn * 64;
  #pragma unroll
  for (int fn = 0; fn < 4; fn++) {
    int col = cbase + fn * 16 + (lane & 15);
    float bv = bias[col];
    #pragma unroll
    for (int fm = 0; fm < 4; fm++) {
      int row0 = rbase + fm * 16;
      #pragma unroll
      for (int r = 0; r < 4; r++)
        f_out[(size_t)(row0 + r) * 1024 + col] = acc[fm][fn][r] + bv;
    }
  }
}

// ---------------- barrier-free windowed decay attention (r4/r5 proven) ----------------
__global__ void __launch_bounds__(512, 2)
attn_kernel(const unsigned short* __restrict__ Qb,
            const unsigned short* __restrict__ Kb,
            const unsigned short* __restrict__ Vt,
            const float* __restrict__ wtab,
            const float* __restrict__ att_mask,
            unsigned short* __restrict__ Yb)
{
  __shared__ alignas(16) unsigned char p_sm[32 * 640];   // P [32][320] bf16, XOR-swizzled
  __shared__ float wl[512];

  const int tid = threadIdx.x;
  const int lane = tid & 63;
  const int w = tid >> 6;

  // XCD-bijective swizzle: 32 consecutive q-blocks per XCD (neighbors share K window)
  const int id = blockIdx.x + blockIdx.y * 128;          // 256 blocks
  const int nid = (id & 7) * 32 + (id >> 3);
  const int qb = nid & 127;
  const int b = nid >> 7;

  const int q0 = qb * 32;
  const int base = b * 4096;
  const int kv0 = q0 - 256;

  if (tid < 512) wl[tid] = wtab[b * 512 + tid];

  const int wq = w >> 2, wk = w & 3;
  const int l15 = lane & 15, lhi = lane >> 4;

  // ---- phase 1: S = Q K^T, fragments straight from global, no barriers ----
  const unsigned short* qptr =
      Qb + (size_t)(base + q0 + wq * 16 + l15) * 1024 + lhi * 8;
  const unsigned short* krow[5];
  #pragma unroll
  for (int f = 0; f < 5; f++) {
    int m = kv0 + wk * 80 + f * 16 + l15;
    m = m < 0 ? 0 : (m > 4095 ? 4095 : m);               // clamped rows weighted 0 later
    krow[f] = Kb + (size_t)(base + m) * 1024 + lhi * 8;
  }

  const f32x4 fz = {0.f, 0.f, 0.f, 0.f};
  f32x4 sacc[5];
  #pragma unroll
  for (int f = 0; f < 5; f++) sacc[f] = fz;

  for (int kk = 0; kk < 32; ++kk) {
    bf16x8 af = *(const bf16x8*)(qptr + kk * 32);
    #pragma unroll
    for (int f = 0; f < 5; f++) {
      bf16x8 bfv = *(const bf16x8*)(krow[f] + kk * 32);
      sacc[f] = __builtin_amdgcn_mfma_f32_16x16x32_bf16(af, bfv, sacc[f], 0, 0, 0);
    }
  }

  __syncthreads();   // wl ready; p_sm free

  // ---- weight + bf16 -> P in LDS ----
  #pragma unroll
  for (int f = 0; f < 5; f++) {
    int jj = wk * 80 + f * 16 + l15;                     // key index in window
    int m = kv0 + jj;
    #pragma unroll
    for (int r = 0; r < 4; r++) {
      int i = wq * 16 + lhi * 4 + r;                     // q row in block
      int d = 256 + i - jj;                              // n - m
      float wgt = (d >= 0 && m >= 0) ? wl[d] : 0.f;
      *(unsigned short*)(p_sm + i * 640 + ((jj * 2) ^ ((i & 7) << 4))) =
          f2bf(sacc[f][r] * wgt);
    }
  }
  __syncthreads();

  // ---- phase 2: y = P @ V, V^T fragments from global ----
  f32x4 yacc[2][8];
  #pragma unroll
  for (int i = 0; i < 2; i++)
    #pragma unroll
    for (int j = 0; j < 8; j++) yacc[i][j] = fz;

  const bool fastv = (kv0 >= 0) && (kv0 <= 3776);
  const unsigned short* vptr[8];
  #pragma unroll
  for (int f = 0; f < 8; f++) {
    int col = w * 128 + f * 16 + l15;
    vptr[f] = Vt + (size_t)col * 8192 + base + kv0 + lhi * 8;
  }

  for (int kt = 0; kt < 10; ++kt) {
    bf16x8 pa[2], vb[8];
    #pragma unroll
    for (int fm = 0; fm < 2; fm++) {
      int row = fm * 16 + l15;
      int cp = kt * 64 + lhi * 16;
      pa[fm] = *(const bf16x8*)(p_sm + row * 640 + (cp ^ ((row & 7) << 4)));
    }
    if (fastv) {
      #pragma unroll
      for (int f = 0; f < 8; f++) vb[f] = *(const bf16x8*)(vptr[f] + kt * 32);
    } else {
      int m = kv0 + kt * 32 + lhi * 8;
      m = m < 0 ? 0 : (m > 4088 ? 4088 : m);             // 8-token group clamp
      #pragma unroll
      for (int f = 0; f < 8; f++) {
        int col = w * 128 + f * 16 + l15;
        vb[f] = *(const bf16x8*)(Vt + (size_t)col * 8192 + base + m);
      }
    }
    #pragma unroll
    for (int fm = 0; fm < 2; fm++)
      #pragma unroll
      for (int fn = 0; fn < 8; fn++)
        yacc[fm][fn] = __builtin_amdgcn_mfma_f32_16x16x32_bf16(pa[fm], vb[fn], yacc[fm][fn], 0, 0, 0);
  }

  // ---- epilogue ----
  #pragma unroll
  for (int fm = 0; fm < 2; fm++) {
    #pragma unroll
    for (int r = 0; r < 4; r++) {
      int n = q0 + fm * 16 + lhi * 4 + r;
      float am = att_mask[base + n];
      #pragma unroll
      for (int fn = 0; fn < 8; fn++) {
        int col = w * 128 + fn * 16 + l15;
        Yb[(size_t)(base + n) * 1024 + col] = f2bf(yacc[fm][fn][r] * am);
      }
    }
  }
}

// ---------------- launcher ----------------
extern "C" void kernel_launch(void* const* d_in, const int* in_sizes, int n_in,
                              void* d_out, int out_size, void* d_ws, size_t ws_size,
                              hipStream_t stream)
{
  (void)in_sizes; (void)n_in; (void)out_size;
  const float* x   = (const float*)d_in[0];
  const float* gm  = (const float*)d_in[1];
  const float* am  = (const float*)d_in[2];
  const float* wq  = (const float*)d_in[3];
  const float* wk  = (const float*)d_in[4];
  const float* wv  = (const float*)d_in[5];
  const float* fcw = (const float*)d_in[6];
  const float* fcb = (const float*)d_in[7];
  float* out = (float*)d_out;

  char* p = (char*)d_ws;
  unsigned short* xb    = (unsigned short*)p; p += (size_t)8192 * 1024 * 2;
  unsigned short* Qb    = (unsigned short*)p; p += (size_t)8192 * 1024 * 2;
  unsigned short* Kb    = (unsigned short*)p; p += (size_t)8192 * 1024 * 2;
  unsigned short* Vt    = (unsigned short*)p; p += (size_t)8192 * 1024 * 2;
  unsigned short* Ybuf  = (unsigned short*)p; p += (size_t)8192 * 1024 * 2;
  unsigned short* WqkvT = (unsigned short*)p; p += (size_t)3072 * 1024 * 2;
  unsigned short* FcwT  = (unsigned short*)p; p += (size_t)1024 * 1024 * 2;
  float* costab = (float*)p; p += (size_t)4096 * 64 * 4;
  float* sintab = (float*)p; p += (size_t)4096 * 64 * 4;
  float* wtab   = (float*)p; p += 4096;
  if ((size_t)(p - (char*)d_ws) > ws_size) return;   // ws too small: fail cleanly

  hipFuncSetAttribute((const void*)gemm256_qkv,
                      hipFuncAttributeMaxDynamicSharedMemorySize, 131072);

  prep_tabs<<<1024, 256, 0, stream>>>(gm, costab, sintab, wtab);
  cvt_x<<<4096, 256, 0, stream>>>(x, xb);
  transpose_cvt4<<<dim3(32, 32, 4), 256, 0, stream>>>(wq, wk, wv, fcw, WqkvT, FcwT);

  gemm256_qkv<<<dim3(32, 12), 512, 131072, stream>>>(xb, WqkvT, Qb, Kb, Vt, costab, sintab);
  attn_kernel<<<dim3(128, 2), 512, 0, stream>>>(Qb, Kb, Vt, wtab, am, Ybuf);
  gemm128_fc<<<dim3(64, 8), 256, 0, stream>>>(Ybuf, FcwT, out, fcb);
}